// Round 1
// baseline (37.873 us; speedup 1.0000x reference)
//
#include <hip/hip_runtime.h>
#include <math.h>

#define RR 8192   // rows
#define FF 4096   // features
#define LL 2048   // gather length
#define RPB 8     // rows per block in main kernel

// ---------------- kernel 1: zero wsum ----------------
__global__ void zero_wsum(float* __restrict__ w) {
    int i = blockIdx.x * 256 + threadIdx.x;
    if (i < 3 * FF) w[i] = 0.0f;
}

// ---------------- kernel 2: scatter weights into per-column sums ----------------
__global__ void scatter_wsum(const int* __restrict__ idx, const float* __restrict__ wts,
                             float* __restrict__ w0, float* __restrict__ w1, float* __restrict__ w2) {
    int l = blockIdx.x * 256 + threadIdx.x;
    if (l < LL) {
        int c = idx[l];
        atomicAdd(w0 + c, wts[l * 3 + 0]);
        atomicAdd(w1 + c, wts[l * 3 + 1]);
        atomicAdd(w2 + c, wts[l * 3 + 2]);
    }
}

// ---------------- kernel 3: dense qkv = inputs @ wsum  (coalesced float4) ----------------
__global__ __launch_bounds__(256) void gemv3(const float* __restrict__ in,
                                             const float* __restrict__ w0,
                                             const float* __restrict__ w1,
                                             const float* __restrict__ w2,
                                             float* __restrict__ qarr,
                                             float* __restrict__ karr,
                                             float* __restrict__ varr) {
    const int t  = threadIdx.x;
    const int r0 = blockIdx.x * RPB;

    float acc[RPB][3];
#pragma unroll
    for (int r = 0; r < RPB; ++r) { acc[r][0] = 0.f; acc[r][1] = 0.f; acc[r][2] = 0.f; }

#pragma unroll
    for (int i = 0; i < FF; i += 1024) {
        const int c = i + t * 4;
        const float4 a0 = *(const float4*)(w0 + c);
        const float4 a1 = *(const float4*)(w1 + c);
        const float4 a2 = *(const float4*)(w2 + c);
#pragma unroll
        for (int r = 0; r < RPB; ++r) {
            const float4 x = *(const float4*)(in + (size_t)(r0 + r) * FF + c);
            acc[r][0] += x.x * a0.x + x.y * a0.y + x.z * a0.z + x.w * a0.w;
            acc[r][1] += x.x * a1.x + x.y * a1.y + x.z * a1.z + x.w * a1.w;
            acc[r][2] += x.x * a2.x + x.y * a2.y + x.z * a2.z + x.w * a2.w;
        }
    }

    // wave-level reduce (64 lanes), then cross-wave via LDS
    const int lane = t & 63, wv = t >> 6;
#pragma unroll
    for (int r = 0; r < RPB; ++r)
#pragma unroll
        for (int j = 0; j < 3; ++j)
            for (int o = 32; o > 0; o >>= 1)
                acc[r][j] += __shfl_down(acc[r][j], o);

    __shared__ float sred[4][RPB * 3];
    if (lane == 0) {
#pragma unroll
        for (int r = 0; r < RPB; ++r)
#pragma unroll
            for (int j = 0; j < 3; ++j)
                sred[wv][r * 3 + j] = acc[r][j];
    }
    __syncthreads();
    if (t < RPB * 3) {
        const float s = sred[0][t] + sred[1][t] + sred[2][t] + sred[3][t];
        const int r = t / 3, j = t - r * 3;
        float* dst = (j == 0) ? qarr : (j == 1) ? karr : varr;
        dst[r0 + r] = s;
    }
}

// ---------------- kernel 4: softmax(last row) @ v -> sigmoid ----------------
__global__ __launch_bounds__(1024) void finalize(const float* __restrict__ qarr,
                                                 const float* __restrict__ karr,
                                                 const float* __restrict__ varr,
                                                 float* __restrict__ out) {
    const int t = threadIdx.x;
    const float q = qarr[RR - 1];   // d_k = 1 -> scale = 1

    float lk[RR / 1024], lv[RR / 1024];
    float m = -INFINITY;
#pragma unroll
    for (int i = 0; i < RR / 1024; ++i) {
        const int r = t + i * 1024;
        lk[i] = q * karr[r];
        lv[i] = varr[r];
        m = fmaxf(m, lk[i]);
    }

    __shared__ float red[16];
    __shared__ float bcast[3];

    // block max
    for (int o = 32; o > 0; o >>= 1) m = fmaxf(m, __shfl_down(m, o));
    if ((t & 63) == 0) red[t >> 6] = m;
    __syncthreads();
    if (t == 0) {
        float x = red[0];
        for (int i = 1; i < 16; ++i) x = fmaxf(x, red[i]);
        bcast[0] = x;
    }
    __syncthreads();
    m = bcast[0];

    float se = 0.f, sv = 0.f;
#pragma unroll
    for (int i = 0; i < RR / 1024; ++i) {
        const float e = expf(lk[i] - m);
        se += e;
        sv += e * lv[i];
    }
    for (int o = 32; o > 0; o >>= 1) { se += __shfl_down(se, o); sv += __shfl_down(sv, o); }
    __shared__ float red2[16];
    if ((t & 63) == 0) { red[t >> 6] = se; red2[t >> 6] = sv; }
    __syncthreads();
    if (t == 0) {
        float a = 0.f, b = 0.f;
        for (int i = 0; i < 16; ++i) { a += red[i]; b += red2[i]; }
        const float val = b / a;
        out[0] = 1.0f / (1.0f + expf(-val));
    }
}

extern "C" void kernel_launch(void* const* d_in, const int* in_sizes, int n_in,
                              void* d_out, int out_size, void* d_ws, size_t ws_size,
                              hipStream_t stream) {
    const float* inputs = (const float*)d_in[0];
    const int*   idx    = (const int*)d_in[1];
    const float* wts    = (const float*)d_in[2];
    float* out = (float*)d_out;

    float* w0   = (float*)d_ws;       // [FF]
    float* w1   = w0 + FF;            // [FF]
    float* w2   = w1 + FF;            // [FF]
    float* qarr = w2 + FF;            // [RR]
    float* karr = qarr + RR;          // [RR]
    float* varr = karr + RR;          // [RR]

    zero_wsum<<<(3 * FF + 255) / 256, 256, 0, stream>>>(w0);
    scatter_wsum<<<(LL + 255) / 256, 256, 0, stream>>>(idx, wts, w0, w1, w2);
    gemv3<<<RR / RPB, 256, 0, stream>>>(inputs, w0, w1, w2, qarr, karr, varr);
    finalize<<<1, 1024, 0, stream>>>(qarr, karr, varr, out);
}